// Round 4
// baseline (216.502 us; speedup 1.0000x reference)
//
#include <hip/hip_runtime.h>

#define N_POINTS  65536
#define N_ANCHORS 1024
#define MAX_PTS   512
#define GX        20             // 20x20 grid, cell = 5.0 (> max box span < 5.0)
#define NC        (GX * GX)      // 400 cells
#define INV_CS    0.2f
#define CAP       512            // per-cell bin capacity (mean 164, +27 sigma)
#define CNT_STRIDE 32            // ints -> 128 B/cell: no atomic cacheline sharing
#define LDS_CAP   1024           // survivors buffered per anchor (max ~750 candidates)
#define PTS_PER_BLK (N_POINTS / N_ANCHORS)   // 64

// ws layout (bytes):
//   0      : int bar[2]                  (grid-barrier counter; memset-zeroed)
//   128    : int cnt[NC * CNT_STRIDE]    (padded counters; memset-zeroed)
//   65536  : float4 binned[NC * CAP]     (x, y, z, asfloat(orig_idx)) = 3.28 MB
#define WS_BAR        0
#define WS_CNT        128
#define WS_ZERO_BYTES (WS_CNT + NC * CNT_STRIDE * 4)   // 51328
#define WS_BINNED     65536

__device__ __forceinline__ int cell_of(float px, float py) {
    int cx = (int)(px * INV_CS);            // coords in [0,100): trunc == floor
    int cy = (int)(py * INV_CS);
    cx = cx > GX - 1 ? GX - 1 : cx;
    cy = cy > GX - 1 ? GX - 1 : cy;
    return cy * GX + cx;
}

// Single fused kernel: phase A bins this block's 64 points; a device-scope
// atomic grid barrier (all 1024 blocks co-resident: 4 waves + 16.4 KB LDS
// -> 8 blocks/CU capacity vs 4 needed); phase B does the per-anchor gather.
__global__ __launch_bounds__(256) void fused_kernel(
    const float* __restrict__ points, const float* __restrict__ anchors,
    int* __restrict__ bar, int* __restrict__ cnt, float4* __restrict__ binned,
    float* __restrict__ out, float* __restrict__ counts)
{
    const int b   = blockIdx.x;
    const int tid = threadIdx.x;

    // ---------- phase A: bin 64 points (order within a cell is irrelevant;
    // phase B re-derives exact first-n order by ranking original indices) ----
    if (tid < PTS_PER_BLK) {
        const int p = b * PTS_PER_BLK + tid;
        const float px = points[p * 3 + 0];
        const float py = points[p * 3 + 1];
        const float pz = points[p * 3 + 2];
        const int c   = cell_of(px, py);
        const int pos = atomicAdd(&cnt[c * CNT_STRIDE], 1);
        if (pos < CAP)   // statistically impossible to exceed; guard anyway
            binned[c * CAP + pos] = make_float4(px, py, pz, __int_as_float(p));
    }

    // ---------- grid barrier (release -> arrive -> spin -> acquire) ----------
    __syncthreads();
    if (tid == 0) {
        __threadfence();                       // release binned/cnt to L2
        atomicAdd(&bar[0], 1);                 // device-scope by default
        int spins = 0;
        while (__hip_atomic_load(&bar[0], __ATOMIC_RELAXED,
                                 __HIP_MEMORY_SCOPE_AGENT) < N_ANCHORS) {
            __builtin_amdgcn_s_sleep(8);       // backoff: don't hammer the line
            if (++spins > (1 << 20)) break;    // safety: never hang the harness
        }
    }
    __syncthreads();
    __threadfence();                           // acquire: L1 invalidate per thread

    // ---------- phase B: anchor gather (block b = anchor b) ----------
    const int a = b;
    const float acx = anchors[a * 6 + 0];
    const float acy = anchors[a * 6 + 1];
    const float hw  = anchors[a * 6 + 3] * 0.5f;   // identical fp32 ops to ref
    const float hl  = anchors[a * 6 + 4] * 0.5f;
    const float h   = anchors[a * 6 + 5];
    const float xmin = acx - hw, xmax = acx + hw;
    const float ymin = acy - hl, ymax = acy + hl;

    // covered cell range: box span < 5.0 = cell size -> <=2 cells per axis
    int cx0 = (int)(fmaxf(xmin, 0.0f) * INV_CS);
    int cx1 = (int)(fmaxf(xmax, 0.0f) * INV_CS);
    int cy0 = (int)(fmaxf(ymin, 0.0f) * INV_CS);
    int cy1 = (int)(fmaxf(ymax, 0.0f) * INV_CS);
    if (cx1 > GX - 1) cx1 = GX - 1;
    if (cy1 > GX - 1) cy1 = GX - 1;
    if (cx0 > GX - 1) cx0 = GX - 1;
    if (cy0 > GX - 1) cy0 = GX - 1;

    int cells[4];
    int nseg = 0;
    cells[nseg++] = cy0 * GX + cx0;
    if (cx1 > cx0)               cells[nseg++] = cy0 * GX + cx1;
    if (cy1 > cy0)               cells[nseg++] = cy1 * GX + cx0;
    if (cx1 > cx0 && cy1 > cy0)  cells[nseg++] = cy1 * GX + cx1;

    int len[4];
    int T = 0;
    #pragma unroll
    for (int s = 0; s < 4; ++s) {
        int l = (s < nseg) ? cnt[cells[s] * CNT_STRIDE] : 0;
        if (l > CAP) l = CAP;
        len[s] = l;
        T += l;
    }

    __shared__ int k;
    __shared__ float4 buf[LDS_CAP];
    if (tid == 0) k = 0;
    __syncthreads();

    for (int idx = tid; idx < T; idx += 256) {
        int s = 0, rel = idx;
        while (rel >= len[s]) { rel -= len[s]; ++s; }
        const float4 p = binned[cells[s] * CAP + rel];
        if (p.x >= xmin && p.x <= xmax &&
            p.y >= ymin && p.y <= ymax &&
            p.z >= 0.0f && p.z <= h) {
            const int slot = atomicAdd(&k, 1);
            if (slot < LDS_CAP) buf[slot] = p;
        }
    }
    __syncthreads();

    const int K  = k;                       // exact uncapped inside-count
    const int Kc = K < LDS_CAP ? K : LDS_CAP;

    float* __restrict__ outa = out + (size_t)a * (MAX_PTS * 3);

    for (int e = tid; e < Kc; e += 256) {
        const float4 pe = buf[e];
        const int ide = __float_as_int(pe.w);
        int rank = 0;
        for (int f = 0; f < Kc; ++f)
            rank += (__float_as_int(buf[f].w) < ide) ? 1 : 0;
        if (rank < MAX_PTS) {
            outa[rank * 3 + 0] = pe.x - acx;
            outa[rank * 3 + 1] = pe.y - acy;
            outa[rank * 3 + 2] = pe.z;      // center z = 0
        }
    }

    // ranks fill [0, min(K,512)) contiguously; zero the poisoned tail
    const int filled = (K < MAX_PTS ? K : MAX_PTS) * 3;
    for (int i = filled + tid; i < MAX_PTS * 3; i += 256) outa[i] = 0.0f;

    if (tid == 0) counts[a] = (float)K;     // whole d_out read back as f32
}

extern "C" void kernel_launch(void* const* d_in, const int* in_sizes, int n_in,
                              void* d_out, int out_size, void* d_ws, size_t ws_size,
                              hipStream_t stream) {
    const float* points  = (const float*)d_in[0];
    const float* anchors = (const float*)d_in[1];

    float* out    = (float*)d_out;                               // (1024,512,3)
    float* counts = (float*)d_out + (size_t)N_ANCHORS * MAX_PTS * 3;

    char* ws = (char*)d_ws;
    int*    bar    = (int*)(ws + WS_BAR);
    int*    cnt    = (int*)(ws + WS_CNT);
    float4* binned = (float4*)(ws + WS_BINNED);

    // zero barrier counter + padded cell counters (ws is poisoned every call)
    hipMemsetAsync(ws, 0, WS_ZERO_BYTES, stream);

    fused_kernel<<<dim3(N_ANCHORS), dim3(256), 0, stream>>>(
        points, anchors, bar, cnt, binned, out, counts);
}

// Round 5
// 80.235 us; speedup vs baseline: 2.6984x; 2.6984x over previous
//
#include <hip/hip_runtime.h>

#define N_POINTS  65536
#define N_ANCHORS 1024
#define MAX_PTS   512
#define GX        20             // 20x20 grid, cell = 5.0 (>= max box span of 5.0)
#define NC        (GX * GX)      // 400 cells
#define INV_CS    0.2f
#define NSUB      8              // scatter blocks; each bins a disjoint point slice
#define CAPS      64             // per (cell, sub-block) capacity: mean 20.5, +9.6 sigma
#define PTS_PER_SBLK (N_POINTS / NSUB)    // 8192
#define LDS_CAP   1024           // survivors buffered per anchor (expected ~52)

// ws layout (bytes) — NOTHING needs pre-zeroing (no memset node):
//   0      : int cnt[NC * NSUB]          (fully written by scatter_kernel)
//   16384  : float4 binned[NC * NSUB * CAPS]  (x,y,z,asfloat(idx)) = 3.28 MB
#define WS_CNT    0
#define WS_BINNED 16384

__device__ __forceinline__ int cell_of(float px, float py) {
    int cx = (int)(px * INV_CS);            // coords in [0,100): trunc == floor
    int cy = (int)(py * INV_CS);
    cx = cx > GX - 1 ? GX - 1 : cx;
    cy = cy > GX - 1 ? GX - 1 : cy;
    return cy * GX + cx;
}

// 8 blocks, each owns a disjoint 8192-point slice. LDS counters (zeroed
// in-kernel) -> no global atomics, no pre-zeroed global state. Order within a
// (cell,sub) segment is irrelevant; anchor re-derives exact first-n order by
// ranking original indices.
__global__ __launch_bounds__(256) void scatter_kernel(
    const float* __restrict__ points, int* __restrict__ cnt,
    float4* __restrict__ binned)
{
    __shared__ int lcnt[NC];
    const int blk = blockIdx.x;
    const int tid = threadIdx.x;

    for (int c = tid; c < NC; c += 256) lcnt[c] = 0;
    __syncthreads();

    const int base = blk * PTS_PER_SBLK;
    for (int it = 0; it < PTS_PER_SBLK / 256; ++it) {
        const int p = base + it * 256 + tid;
        const float px = points[p * 3 + 0];
        const float py = points[p * 3 + 1];
        const float pz = points[p * 3 + 2];
        const int c    = cell_of(px, py);
        const int slot = atomicAdd(&lcnt[c], 1);      // LDS atomic
        if (slot < CAPS)   // statistically impossible to exceed; guard anyway
            binned[(c * NSUB + blk) * CAPS + slot] =
                make_float4(px, py, pz, __int_as_float(p));
    }
    __syncthreads();
    for (int c = tid; c < NC; c += 256) {
        int l = lcnt[c];
        cnt[c * NSUB + blk] = l < CAPS ? l : CAPS;
    }
}

// One block (256 thr) per anchor. Box spans <=2 cells/axis -> <=4 cells, each
// split into NSUB segments. Build a flattened segment table in LDS, scan all
// candidates load-balanced, append survivors via LDS atomic, then slot = rank
// of original index (exact first-n semantics regardless of append order).
__global__ __launch_bounds__(256) void anchor_kernel(
    const float4* __restrict__ binned, const int* __restrict__ cnt,
    const float* __restrict__ anchors, float* __restrict__ out,
    float* __restrict__ counts)
{
    const int a   = blockIdx.x;
    const int tid = threadIdx.x;

    const float acx = anchors[a * 6 + 0];
    const float acy = anchors[a * 6 + 1];
    const float hw  = anchors[a * 6 + 3] * 0.5f;   // identical fp32 ops to ref
    const float hl  = anchors[a * 6 + 4] * 0.5f;
    const float h   = anchors[a * 6 + 5];
    const float xmin = acx - hw, xmax = acx + hw;
    const float ymin = acy - hl, ymax = acy + hl;

    // covered cell range (cell_of is monotone; coords in [0,100))
    int cx0 = (int)(fmaxf(xmin, 0.0f) * INV_CS);
    int cx1 = (int)(fmaxf(xmax, 0.0f) * INV_CS);
    int cy0 = (int)(fmaxf(ymin, 0.0f) * INV_CS);
    int cy1 = (int)(fmaxf(ymax, 0.0f) * INV_CS);
    if (cx1 > GX - 1) cx1 = GX - 1;
    if (cy1 > GX - 1) cy1 = GX - 1;
    if (cx0 > GX - 1) cx0 = GX - 1;
    if (cy0 > GX - 1) cy0 = GX - 1;

    // unique cells (1, 2, or 4) as scalars (avoid register-array dyn indexing)
    const int cell0 = cy0 * GX + cx0;
    const int cell1 = cy0 * GX + cx1;
    const int cell2 = cy1 * GX + cx0;
    const int cell3 = cy1 * GX + cx1;
    int ncells = 1;
    if (cx1 > cx0) ncells = 2;
    if (cy1 > cy0) ncells = (cx1 > cx0) ? 4 : 2;
    // ordered unique list: c0, (c1 if cx1>cx0), (c2 if cy1>cy0), (c3 if both)
    const int nseg = ncells * NSUB;

    __shared__ int segLen[4 * NSUB];
    __shared__ int segBase[4 * NSUB];      // element base into binned
    __shared__ int segStart[4 * NSUB + 1]; // prefix of lengths
    __shared__ int k;
    __shared__ float4 buf[LDS_CAP];

    if (tid < nseg) {
        const int q  = tid >> 3;           // which cell slot 0..3
        int ci;
        if (ncells == 1)       ci = cell0;
        else if (ncells == 2)  ci = (q == 0) ? cell0 : ((cx1 > cx0) ? cell1 : cell2);
        else                   ci = (q == 0) ? cell0 : (q == 1) ? cell1
                                   : (q == 2) ? cell2 : cell3;
        const int sub = tid & (NSUB - 1);
        int l = cnt[ci * NSUB + sub];
        if (l > CAPS) l = CAPS;
        segLen[tid]  = l;
        segBase[tid] = (ci * NSUB + sub) * CAPS;
    }
    if (tid == 0) k = 0;
    __syncthreads();
    if (tid == 0) {
        int acc = 0;
        for (int s = 0; s < nseg; ++s) { segStart[s] = acc; acc += segLen[s]; }
        segStart[nseg] = acc;
    }
    __syncthreads();

    const int T = segStart[nseg];
    for (int idx = tid; idx < T; idx += 256) {
        int s = 0;
        while (segStart[s + 1] <= idx) ++s;    // <=32 LDS broadcast compares
        const float4 p = binned[segBase[s] + (idx - segStart[s])];
        if (p.x >= xmin && p.x <= xmax &&
            p.y >= ymin && p.y <= ymax &&
            p.z >= 0.0f && p.z <= h) {
            const int slot = atomicAdd(&k, 1);
            if (slot < LDS_CAP) buf[slot] = p;
        }
    }
    __syncthreads();

    const int K  = k;                       // exact uncapped inside-count
    const int Kc = K < LDS_CAP ? K : LDS_CAP;

    float* __restrict__ outa = out + (size_t)a * (MAX_PTS * 3);

    for (int e = tid; e < Kc; e += 256) {
        const float4 pe = buf[e];
        const int ide = __float_as_int(pe.w);
        int rank = 0;
        for (int f = 0; f < Kc; ++f)
            rank += (__float_as_int(buf[f].w) < ide) ? 1 : 0;
        if (rank < MAX_PTS) {
            outa[rank * 3 + 0] = pe.x - acx;
            outa[rank * 3 + 1] = pe.y - acy;
            outa[rank * 3 + 2] = pe.z;      // center z = 0
        }
    }

    // ranks fill [0, min(K,512)) contiguously; zero the poisoned tail
    // (coalesced scalar dword stores -> full lines; not a bottleneck)
    const int filled = (K < MAX_PTS ? K : MAX_PTS) * 3;
    for (int i = filled + tid; i < MAX_PTS * 3; i += 256) outa[i] = 0.0f;

    if (tid == 0) counts[a] = (float)K;     // whole d_out read back as f32
}

extern "C" void kernel_launch(void* const* d_in, const int* in_sizes, int n_in,
                              void* d_out, int out_size, void* d_ws, size_t ws_size,
                              hipStream_t stream) {
    const float* points  = (const float*)d_in[0];
    const float* anchors = (const float*)d_in[1];

    float* out    = (float*)d_out;                               // (1024,512,3)
    float* counts = (float*)d_out + (size_t)N_ANCHORS * MAX_PTS * 3;

    char* ws = (char*)d_ws;
    int*    cnt    = (int*)(ws + WS_CNT);
    float4* binned = (float4*)(ws + WS_BINNED);

    // 2 nodes, no memset: cnt is fully written by scatter_kernel.
    scatter_kernel<<<dim3(NSUB),      dim3(256), 0, stream>>>(points, cnt, binned);
    anchor_kernel <<<dim3(N_ANCHORS), dim3(256), 0, stream>>>(binned, cnt, anchors, out, counts);
}